// Round 5
// baseline (518.555 us; speedup 1.0000x reference)
//
#include <hip/hip_runtime.h>
#include <hip/hip_bf16.h>

// NGCF fused propagation, N=8192, D=64.
//  pass1: read fp32 adj once -> rs, cs + adjbf (bf16)
//  prep : Bti[d][j] = invc[j]*[user@W1 | item][j][d] ; Btu[d][i] = invr[i]*[item@W1 | user][i][d]
//  gemm : z=0: Pi[s] = adjbf[:, ks] @ Bti[:, ks]^T   (private per-split slice, plain stores)
//         z=1: Pu[s] = adjbf[ks, :]^T @ Btu[:, ks]^T (transpose via swizzled LDS scatter)
//  epi  : sum slices; out = leaky( inv*P[:,0:64] + (tgt_elem*inv*P[:,64:128])@W2 + tgt )
// This round: KSPLIT 4->8 with the merged single dispatch -> 1024 blocks = 3 blocks/CU
// (was 2/CU): +50% waves/SIMD to hide A-staging HBM latency (m114 TLP-overlap regime).

#define LRELU_ALPHA 0.2f
constexpr int N = 8192;
constexpr int KSPLIT = 8;
constexpr int KC = N / KSPLIT;   // 1024 K per block, 16 BK-steps of 64

typedef __attribute__((ext_vector_type(4))) float f32x4;
typedef __attribute__((ext_vector_type(8))) __bf16 bf16x8;

__device__ __forceinline__ unsigned short f2bf(float x) {
    unsigned u = __builtin_bit_cast(unsigned, x);
    u += 0x7fffu + ((u >> 16) & 1u);   // RNE
    return (unsigned short)(u >> 16);
}
__device__ __forceinline__ f32x4 mfma16(uint4 a, uint4 b, f32x4 c) {
    return __builtin_amdgcn_mfma_f32_16x16x32_bf16(
        __builtin_bit_cast(bf16x8, a), __builtin_bit_cast(bf16x8, b), c, 0, 0, 0);
}
__device__ __forceinline__ void stage16(const void* g, void* l) {
    __builtin_amdgcn_global_load_lds(
        (const __attribute__((address_space(1))) unsigned int*)g,
        (__attribute__((address_space(3))) unsigned int*)l, 16, 0, 0);
}

// ---------------- pass1: sums + bf16 copy ----------------
__global__ __launch_bounds__(256) void pass1_kernel(
    const float* __restrict__ adj,
    float* __restrict__ rs, float* __restrict__ cs,
    unsigned short* __restrict__ adjbf) {
    __shared__ float rowsumL[128];
    __shared__ float4 colpart4[8][32];
    const int tid = threadIdx.x;
    const int g32 = tid >> 5, l32 = tid & 31;
    const int r0 = blockIdx.y * 128, c0 = blockIdx.x * 128;

    float4 colacc = make_float4(0.f, 0.f, 0.f, 0.f);
#pragma unroll 4
    for (int s = 0; s < 16; ++s) {
        const int i = s * 8 + g32;
        float4 v = *reinterpret_cast<const float4*>(adj + (size_t)(r0 + i) * N + c0 + l32 * 4);
        colacc.x += v.x; colacc.y += v.y; colacc.z += v.z; colacc.w += v.w;
        ushort4 b;
        b.x = f2bf(v.x); b.y = f2bf(v.y); b.z = f2bf(v.z); b.w = f2bf(v.w);
        *reinterpret_cast<ushort4*>(adjbf + (size_t)(r0 + i) * N + c0 + l32 * 4) = b;
        float rp = (v.x + v.y) + (v.z + v.w);
#pragma unroll
        for (int off = 16; off > 0; off >>= 1) rp += __shfl_down(rp, off, 32);
        if (l32 == 0) rowsumL[i] = rp;
    }
    colpart4[g32][l32] = colacc;
    __syncthreads();

    if (tid < 128) {
        atomicAdd(rs + r0 + tid, rowsumL[tid]);
        const float* cp = (const float*)colpart4;
        float s = 0.f;
#pragma unroll
        for (int w = 0; w < 8; ++w) s += cp[w * 128 + tid];
        atomicAdd(cs + c0 + tid, s);
    }
}

// ---------------- build the two RHS matrices (transposed, bf16) ----------------
__global__ __launch_bounds__(256) void prep_kernel(
    const float* __restrict__ user, const float* __restrict__ item,
    const float* __restrict__ W1, const float* __restrict__ rs, const float* __restrict__ cs,
    unsigned short* __restrict__ Bti, unsigned short* __restrict__ Btu) {
    __shared__ float W1s[64][65];
    __shared__ float ru[64][65];
    __shared__ float ri[64][65];
    __shared__ unsigned short tile[128][66];
    const int tid = threadIdx.x;
    const int j0 = blockIdx.x * 64;
    for (int t = tid; t < 64 * 64; t += 256) {
        W1s[t >> 6][t & 63] = W1[t];
        ru[t >> 6][t & 63] = user[(size_t)j0 * 64 + t];
        ri[t >> 6][t & 63] = item[(size_t)j0 * 64 + t];
    }
    __syncthreads();
    for (int pass = 0; pass < 2; ++pass) {
        for (int it = 0; it < 32; ++it) {
            int idx = tid + 256 * it;
            int d = idx & 127, jl = idx >> 7;
            float scale = (pass == 0) ? rsqrtf(cs[j0 + jl]) : rsqrtf(rs[j0 + jl]);
            float v;
            if (d < 64) {
                const float(*src)[65] = (pass == 0) ? ru : ri;
                float acc = 0.f;
#pragma unroll
                for (int k = 0; k < 64; ++k) acc += src[jl][k] * W1s[k][d];
                v = acc;
            } else {
                const float(*src)[65] = (pass == 0) ? ri : ru;
                v = src[jl][d - 64];
            }
            tile[d][jl] = f2bf(v * scale);
        }
        __syncthreads();
        unsigned short* Bt = (pass == 0) ? Bti : Btu;
        for (int t = tid; t < 128 * 64; t += 256) {
            int d = t >> 6, jl = t & 63;
            Bt[(size_t)d * N + j0 + jl] = tile[d][jl];
        }
        __syncthreads();
    }
}

// ---------------- merged gemm: z=0 N-path (Pi), z=1 T-path (Pu) ----------------
// Block: 128 out-rows x 128 cols x KC. 4 waves 2x2; each wave 64x64 (4x4 MFMA tiles).
// LDS XOR-swizzled; stores go to private per-(blockIdx.y) slices (no atomics).
__global__ __launch_bounds__(256, 3) void gemm_kernel(
    const unsigned short* __restrict__ A,
    const unsigned short* __restrict__ Bti, const unsigned short* __restrict__ Btu,
    float* __restrict__ Pi, float* __restrict__ Pu) {
    __shared__ unsigned short Xs[128 * 64];   // As (N-path) or Ts (T-path)
    __shared__ unsigned short Bs[128 * 64];

    const bool isT = blockIdx.z != 0;
    const unsigned short* __restrict__ Bt = isT ? Btu : Bti;
    float* __restrict__ Pw = (isT ? Pu : Pi) + (size_t)blockIdx.y * ((size_t)N * 128);

    const int lane = threadIdx.x & 63, wave = threadIdx.x >> 6;
    const int q = lane >> 4, lm = lane & 15;
    const int wr = wave >> 1, wc = wave & 1;
    const int x0 = blockIdx.x * 128;           // m0 (N-path) or j0 (T-path)
    const int kbase = blockIdx.y * KC;

    const int sr = wave * 32 + (lane >> 3);
    const int sc = lane & 7;

    f32x4 acc[4][4];
#pragma unroll
    for (int mt = 0; mt < 4; ++mt)
#pragma unroll
        for (int nt = 0; nt < 4; ++nt) acc[mt][nt] = (f32x4){0.f, 0.f, 0.f, 0.f};

    if (!isT) {
        // ---- N-path: Pi[m, :] = sum_k A[m, k] * Bt[:, k] ----
        for (int step = 0; step < KC / 64; ++step) {
            const int k0 = kbase + step * 64;
#pragma unroll
            for (int t = 0; t < 4; ++t) {
                const int r = sr + t * 8;
                const int koff = (sc ^ (r & 7)) * 8;
                stage16(A + (size_t)(x0 + r) * N + k0 + koff, &Xs[(wave * 32 + t * 8) * 64]);
                stage16(Bt + (size_t)r * N + k0 + koff, &Bs[(wave * 32 + t * 8) * 64]);
            }
            __syncthreads();
#pragma unroll
            for (int kk = 0; kk < 2; ++kk) {
                uint4 af[4], bf[4];
#pragma unroll
                for (int mt = 0; mt < 4; ++mt) {
                    const int ml = wr * 64 + mt * 16 + lm;
                    af[mt] = *reinterpret_cast<const uint4*>(
                        &Xs[ml * 64 + (((kk * 4 + q) ^ (ml & 7)) * 8)]);
                }
#pragma unroll
                for (int nt = 0; nt < 4; ++nt) {
                    const int nl = wc * 64 + nt * 16 + lm;
                    bf[nt] = *reinterpret_cast<const uint4*>(
                        &Bs[nl * 64 + (((kk * 4 + q) ^ (nl & 7)) * 8)]);
                }
#pragma unroll
                for (int mt = 0; mt < 4; ++mt)
#pragma unroll
                    for (int nt = 0; nt < 4; ++nt)
                        acc[mt][nt] = mfma16(af[mt], bf[nt], acc[mt][nt]);
            }
            __syncthreads();
        }
    } else {
        // ---- T-path: Pu[j, :] = sum_i A[i, j] * Bt[:, i]; transpose via LDS scatter ----
        for (int step = 0; step < KC / 64; ++step) {
            const int ibase = kbase + step * 64;
            uint4 g[4];
#pragma unroll
            for (int p = 0; p < 4; ++p) {
                const int jc = wave + p * 4;
                g[p] = *reinterpret_cast<const uint4*>(
                    A + (size_t)(ibase + lane) * N + x0 + jc * 8);
            }
            __syncthreads();   // prior step's MFMA reads done before LDS overwrite
#pragma unroll
            for (int t = 0; t < 4; ++t) {
                const int r = sr + t * 8;
                const int koff = (sc ^ (r & 7)) * 8;
                stage16(Bt + (size_t)r * N + ibase + koff, &Bs[(wave * 32 + t * 8) * 64]);
            }
            // transposed scatter: per instr j wave-uniform, lanes span i=0..63 contiguous
#pragma unroll
            for (int p = 0; p < 4; ++p) {
                const int jl = (wave + p * 4) * 8;
                const unsigned short* e = reinterpret_cast<const unsigned short*>(&g[p]);
#pragma unroll
                for (int k = 0; k < 8; ++k) {
                    Xs[(jl + k) * 64 + (lane ^ (k * 8))] = e[k];
                }
            }
            __syncthreads();
#pragma unroll
            for (int kk = 0; kk < 2; ++kk) {
                uint4 af[4], bf[4];
#pragma unroll
                for (int mt = 0; mt < 4; ++mt) {
                    const int ml = wr * 64 + mt * 16 + lm;
                    af[mt] = *reinterpret_cast<const uint4*>(
                        &Xs[ml * 64 + ((kk * 32 + q * 8) ^ ((ml & 7) * 8))]);
                }
#pragma unroll
                for (int nt = 0; nt < 4; ++nt) {
                    const int nl = wc * 64 + nt * 16 + lm;
                    bf[nt] = *reinterpret_cast<const uint4*>(
                        &Bs[nl * 64 + (((kk * 4 + q) ^ (nl & 7)) * 8)]);
                }
#pragma unroll
                for (int mt = 0; mt < 4; ++mt)
#pragma unroll
                    for (int nt = 0; nt < 4; ++nt)
                        acc[mt][nt] = mfma16(af[mt], bf[nt], acc[mt][nt]);
            }
        }
    }

#pragma unroll
    for (int mt = 0; mt < 4; ++mt)
#pragma unroll
        for (int nt = 0; nt < 4; ++nt)
#pragma unroll
            for (int r = 0; r < 4; ++r) {
                const int row = x0 + wr * 64 + mt * 16 + q * 4 + r;
                const int col = wc * 64 + nt * 16 + lm;
                Pw[(size_t)row * 128 + col] = acc[mt][nt][r];
            }
}

// ---------------- epilogue: slice-sum, scale, (g)@W2, +tgt, leaky, write ----------------
__global__ __launch_bounds__(256) void epilogue_kernel(
    const float* __restrict__ user, const float* __restrict__ item,
    const float* __restrict__ W2, const float* __restrict__ rs, const float* __restrict__ cs,
    const float* __restrict__ Pi, const float* __restrict__ Pu,
    float* __restrict__ out) {
    __shared__ float W2s[64][65];
    __shared__ float gi[4][64];
    __shared__ float gu[4][64];
    const int tid = threadIdx.x;
    for (int t = tid; t < 64 * 64; t += 256) W2s[t >> 6][t & 63] = W2[t];
    const int r4 = tid >> 6, d = tid & 63;
    for (int p = 0; p < 4; ++p) {
        const int row = blockIdx.x * 16 + p * 4 + r4;
        const float invr = rsqrtf(rs[row]);
        const float invc = rsqrtf(cs[row]);
        const float u_rd = user[(size_t)row * 64 + d];
        const float i_rd = item[(size_t)row * 64 + d];
        float pi_lo = 0.f, pi_hi = 0.f, pu_lo = 0.f, pu_hi = 0.f;
#pragma unroll
        for (int s = 0; s < KSPLIT; ++s) {
            const size_t off = (size_t)s * N * 128 + (size_t)row * 128;
            pi_lo += Pi[off + d];
            pi_hi += Pi[off + 64 + d];
            pu_lo += Pu[off + d];
            pu_hi += Pu[off + 64 + d];
        }
        __syncthreads();
        gi[r4][d] = u_rd * invr * pi_hi;
        gu[r4][d] = i_rd * invc * pu_hi;
        __syncthreads();
        float vi = invr * pi_lo + i_rd;
        float vu = invc * pu_lo + u_rd;
#pragma unroll
        for (int e = 0; e < 64; ++e) {
            vi += gi[r4][e] * W2s[e][d];
            vu += gu[r4][e] * W2s[e][d];
        }
        vi = vi > 0.f ? vi : LRELU_ALPHA * vi;
        vu = vu > 0.f ? vu : LRELU_ALPHA * vu;
        out[(size_t)row * 64 + d] = vu;
        out[(size_t)N * 64 + (size_t)row * 64 + d] = vi;
    }
}

extern "C" void kernel_launch(void* const* d_in, const int* in_sizes, int n_in,
                              void* d_out, int out_size, void* d_ws, size_t ws_size,
                              hipStream_t stream) {
    const float* user = (const float*)d_in[0];
    const float* item = (const float*)d_in[1];
    const float* adj  = (const float*)d_in[2];
    const float* W1   = (const float*)d_in[3];
    const float* W2   = (const float*)d_in[4];
    float* out = (float*)d_out;

    char* w = (char*)d_ws;
    float* Pi = (float*)w;  w += (size_t)KSPLIT * N * 128 * 4;   // 32 MB
    float* Pu = (float*)w;  w += (size_t)KSPLIT * N * 128 * 4;   // 32 MB
    float* rs = (float*)w;  w += (size_t)N * 4;
    float* cs = (float*)w;  w += (size_t)N * 4;
    unsigned short* Bti = (unsigned short*)w;  w += (size_t)N * 128 * 2;
    unsigned short* Btu = (unsigned short*)w;  w += (size_t)N * 128 * 2;
    unsigned short* adjbf = (unsigned short*)w;

    // only rs/cs need zero-init (P slices are fully overwritten)
    (void)hipMemsetAsync(rs, 0, (size_t)2 * N * 4, stream);

    pass1_kernel<<<dim3(N / 128, N / 128), 256, 0, stream>>>(adj, rs, cs, adjbf);
    prep_kernel<<<N / 64, 256, 0, stream>>>(user, item, W1, rs, cs, Bti, Btu);
    gemm_kernel<<<dim3(N / 128, KSPLIT, 2), 256, 0, stream>>>(adjbf, Bti, Btu, Pi, Pu);
    epilogue_kernel<<<N / 16, 256, 0, stream>>>(user, item, W2, rs, cs, Pi, Pu, out);
}

// Round 6
// 511.148 us; speedup vs baseline: 1.0145x; 1.0145x over previous
//
#include <hip/hip_runtime.h>
#include <hip/hip_bf16.h>

// NGCF fused propagation, N=8192, D=64.
//  pass1: read fp32 adj once -> rs, cs + adjbf (bf16)   [this round: VALU diet —
//         HW cvt_pk via __bf16 casts + LDS row-partials instead of shuffle trees]
//  prep : Bti[d][j] = invc[j]*[user@W1 | item][j][d] ; Btu[d][i] = invr[i]*[item@W1 | user][i][d]
//  gemm : z=0: Pi[s] = adjbf[:, ks] @ Bti[:, ks]^T   (private per-split slice, plain stores)
//         z=1: Pu[s] = adjbf[ks, :]^T @ Btu[:, ks]^T (transpose via swizzled LDS scatter)
//  epi  : sum slices; out = leaky( inv*P[:,0:64] + (tgt_elem*inv*P[:,64:128])@W2 + tgt )

#define LRELU_ALPHA 0.2f
constexpr int N = 8192;
constexpr int KSPLIT = 8;
constexpr int KC = N / KSPLIT;   // 1024 K per block, 16 BK-steps of 64

typedef __attribute__((ext_vector_type(4))) float f32x4;
typedef __attribute__((ext_vector_type(8))) __bf16 bf16x8;

__device__ __forceinline__ unsigned short f2bf(float x) {
    // plain cast: compiler emits v_cvt_pk_bf16_f32 (RNE) when paired
    return __builtin_bit_cast(unsigned short, (__bf16)x);
}
__device__ __forceinline__ f32x4 mfma16(uint4 a, uint4 b, f32x4 c) {
    return __builtin_amdgcn_mfma_f32_16x16x32_bf16(
        __builtin_bit_cast(bf16x8, a), __builtin_bit_cast(bf16x8, b), c, 0, 0, 0);
}
__device__ __forceinline__ void stage16(const void* g, void* l) {
    __builtin_amdgcn_global_load_lds(
        (const __attribute__((address_space(1))) unsigned int*)g,
        (__attribute__((address_space(3))) unsigned int*)l, 16, 0, 0);
}

// ---------------- pass1: sums + bf16 copy (VALU-lean) ----------------
__global__ __launch_bounds__(256) void pass1_kernel(
    const float* __restrict__ adj,
    float* __restrict__ rs, float* __restrict__ cs,
    unsigned short* __restrict__ adjbf) {
    __shared__ float rowpart[128][33];     // [row][lane-group partial], +1 pad: 2-way banks
    __shared__ float4 colpart4[8][32];
    const int tid = threadIdx.x;
    const int g32 = tid >> 5, l32 = tid & 31;
    const int r0 = blockIdx.y * 128, c0 = blockIdx.x * 128;

    float4 colacc = make_float4(0.f, 0.f, 0.f, 0.f);
#pragma unroll 4
    for (int s = 0; s < 16; ++s) {
        const int i = s * 8 + g32;
        float4 v = *reinterpret_cast<const float4*>(adj + (size_t)(r0 + i) * N + c0 + l32 * 4);
        colacc.x += v.x; colacc.y += v.y; colacc.z += v.z; colacc.w += v.w;
        ushort4 b;
        b.x = f2bf(v.x); b.y = f2bf(v.y); b.z = f2bf(v.z); b.w = f2bf(v.w);
        *reinterpret_cast<ushort4*>(adjbf + (size_t)(r0 + i) * N + c0 + l32 * 4) = b;
        rowpart[i][l32] = (v.x + v.y) + (v.z + v.w);   // 1 ds_write replaces 5x shfl+add
    }
    colpart4[g32][l32] = colacc;
    __syncthreads();

    if (tid < 128) {
        float rsum = 0.f;
#pragma unroll
        for (int w = 0; w < 32; ++w) rsum += rowpart[tid][w];
        atomicAdd(rs + r0 + tid, rsum);
        const float* cp = (const float*)colpart4;
        float s = 0.f;
#pragma unroll
        for (int w = 0; w < 8; ++w) s += cp[w * 128 + tid];
        atomicAdd(cs + c0 + tid, s);
    }
}

// ---------------- build the two RHS matrices (transposed, bf16) ----------------
__global__ __launch_bounds__(256) void prep_kernel(
    const float* __restrict__ user, const float* __restrict__ item,
    const float* __restrict__ W1, const float* __restrict__ rs, const float* __restrict__ cs,
    unsigned short* __restrict__ Bti, unsigned short* __restrict__ Btu) {
    __shared__ float W1s[64][65];
    __shared__ float ru[64][65];
    __shared__ float ri[64][65];
    __shared__ unsigned short tile[128][66];
    const int tid = threadIdx.x;
    const int j0 = blockIdx.x * 64;
    for (int t = tid; t < 64 * 64; t += 256) {
        W1s[t >> 6][t & 63] = W1[t];
        ru[t >> 6][t & 63] = user[(size_t)j0 * 64 + t];
        ri[t >> 6][t & 63] = item[(size_t)j0 * 64 + t];
    }
    __syncthreads();
    for (int pass = 0; pass < 2; ++pass) {
        for (int it = 0; it < 32; ++it) {
            int idx = tid + 256 * it;
            int d = idx & 127, jl = idx >> 7;
            float scale = (pass == 0) ? rsqrtf(cs[j0 + jl]) : rsqrtf(rs[j0 + jl]);
            float v;
            if (d < 64) {
                const float(*src)[65] = (pass == 0) ? ru : ri;
                float acc = 0.f;
#pragma unroll
                for (int k = 0; k < 64; ++k) acc += src[jl][k] * W1s[k][d];
                v = acc;
            } else {
                const float(*src)[65] = (pass == 0) ? ri : ru;
                v = src[jl][d - 64];
            }
            tile[d][jl] = f2bf(v * scale);
        }
        __syncthreads();
        unsigned short* Bt = (pass == 0) ? Bti : Btu;
        for (int t = tid; t < 128 * 64; t += 256) {
            int d = t >> 6, jl = t & 63;
            Bt[(size_t)d * N + j0 + jl] = tile[d][jl];
        }
        __syncthreads();
    }
}

// ---------------- merged gemm: z=0 N-path (Pi), z=1 T-path (Pu) ----------------
// Block: 128 out-rows x 128 cols x KC. 4 waves 2x2; each wave 64x64 (4x4 MFMA tiles).
// LDS XOR-swizzled; stores go to private per-(blockIdx.y) slices (no atomics).
__global__ __launch_bounds__(256, 3) void gemm_kernel(
    const unsigned short* __restrict__ A,
    const unsigned short* __restrict__ Bti, const unsigned short* __restrict__ Btu,
    float* __restrict__ Pi, float* __restrict__ Pu) {
    __shared__ unsigned short Xs[128 * 64];   // As (N-path) or Ts (T-path)
    __shared__ unsigned short Bs[128 * 64];

    const bool isT = blockIdx.z != 0;
    const unsigned short* __restrict__ Bt = isT ? Btu : Bti;
    float* __restrict__ Pw = (isT ? Pu : Pi) + (size_t)blockIdx.y * ((size_t)N * 128);

    const int lane = threadIdx.x & 63, wave = threadIdx.x >> 6;
    const int q = lane >> 4, lm = lane & 15;
    const int wr = wave >> 1, wc = wave & 1;
    const int x0 = blockIdx.x * 128;           // m0 (N-path) or j0 (T-path)
    const int kbase = blockIdx.y * KC;

    const int sr = wave * 32 + (lane >> 3);
    const int sc = lane & 7;

    f32x4 acc[4][4];
#pragma unroll
    for (int mt = 0; mt < 4; ++mt)
#pragma unroll
        for (int nt = 0; nt < 4; ++nt) acc[mt][nt] = (f32x4){0.f, 0.f, 0.f, 0.f};

    if (!isT) {
        // ---- N-path: Pi[m, :] = sum_k A[m, k] * Bt[:, k] ----
        for (int step = 0; step < KC / 64; ++step) {
            const int k0 = kbase + step * 64;
#pragma unroll
            for (int t = 0; t < 4; ++t) {
                const int r = sr + t * 8;
                const int koff = (sc ^ (r & 7)) * 8;
                stage16(A + (size_t)(x0 + r) * N + k0 + koff, &Xs[(wave * 32 + t * 8) * 64]);
                stage16(Bt + (size_t)r * N + k0 + koff, &Bs[(wave * 32 + t * 8) * 64]);
            }
            __syncthreads();
#pragma unroll
            for (int kk = 0; kk < 2; ++kk) {
                uint4 af[4], bf[4];
#pragma unroll
                for (int mt = 0; mt < 4; ++mt) {
                    const int ml = wr * 64 + mt * 16 + lm;
                    af[mt] = *reinterpret_cast<const uint4*>(
                        &Xs[ml * 64 + (((kk * 4 + q) ^ (ml & 7)) * 8)]);
                }
#pragma unroll
                for (int nt = 0; nt < 4; ++nt) {
                    const int nl = wc * 64 + nt * 16 + lm;
                    bf[nt] = *reinterpret_cast<const uint4*>(
                        &Bs[nl * 64 + (((kk * 4 + q) ^ (nl & 7)) * 8)]);
                }
#pragma unroll
                for (int mt = 0; mt < 4; ++mt)
#pragma unroll
                    for (int nt = 0; nt < 4; ++nt)
                        acc[mt][nt] = mfma16(af[mt], bf[nt], acc[mt][nt]);
            }
            __syncthreads();
        }
    } else {
        // ---- T-path: Pu[j, :] = sum_i A[i, j] * Bt[:, i]; transpose via LDS scatter ----
        for (int step = 0; step < KC / 64; ++step) {
            const int ibase = kbase + step * 64;
            uint4 g[4];
#pragma unroll
            for (int p = 0; p < 4; ++p) {
                const int jc = wave + p * 4;
                g[p] = *reinterpret_cast<const uint4*>(
                    A + (size_t)(ibase + lane) * N + x0 + jc * 8);
            }
            __syncthreads();   // prior step's MFMA reads done before LDS overwrite
#pragma unroll
            for (int t = 0; t < 4; ++t) {
                const int r = sr + t * 8;
                const int koff = (sc ^ (r & 7)) * 8;
                stage16(Bt + (size_t)r * N + ibase + koff, &Bs[(wave * 32 + t * 8) * 64]);
            }
            // transposed scatter: per instr j wave-uniform, lanes span i=0..63 contiguous
#pragma unroll
            for (int p = 0; p < 4; ++p) {
                const int jl = (wave + p * 4) * 8;
                const unsigned short* e = reinterpret_cast<const unsigned short*>(&g[p]);
#pragma unroll
                for (int k = 0; k < 8; ++k) {
                    Xs[(jl + k) * 64 + (lane ^ (k * 8))] = e[k];
                }
            }
            __syncthreads();
#pragma unroll
            for (int kk = 0; kk < 2; ++kk) {
                uint4 af[4], bf[4];
#pragma unroll
                for (int mt = 0; mt < 4; ++mt) {
                    const int ml = wr * 64 + mt * 16 + lm;
                    af[mt] = *reinterpret_cast<const uint4*>(
                        &Xs[ml * 64 + ((kk * 32 + q * 8) ^ ((ml & 7) * 8))]);
                }
#pragma unroll
                for (int nt = 0; nt < 4; ++nt) {
                    const int nl = wc * 64 + nt * 16 + lm;
                    bf[nt] = *reinterpret_cast<const uint4*>(
                        &Bs[nl * 64 + (((kk * 4 + q) ^ (nl & 7)) * 8)]);
                }
#pragma unroll
                for (int mt = 0; mt < 4; ++mt)
#pragma unroll
                    for (int nt = 0; nt < 4; ++nt)
                        acc[mt][nt] = mfma16(af[mt], bf[nt], acc[mt][nt]);
            }
        }
    }

#pragma unroll
    for (int mt = 0; mt < 4; ++mt)
#pragma unroll
        for (int nt = 0; nt < 4; ++nt)
#pragma unroll
            for (int r = 0; r < 4; ++r) {
                const int row = x0 + wr * 64 + mt * 16 + q * 4 + r;
                const int col = wc * 64 + nt * 16 + lm;
                Pw[(size_t)row * 128 + col] = acc[mt][nt][r];
            }
}

// ---------------- epilogue: slice-sum, scale, (g)@W2, +tgt, leaky, write ----------------
__global__ __launch_bounds__(256) void epilogue_kernel(
    const float* __restrict__ user, const float* __restrict__ item,
    const float* __restrict__ W2, const float* __restrict__ rs, const float* __restrict__ cs,
    const float* __restrict__ Pi, const float* __restrict__ Pu,
    float* __restrict__ out) {
    __shared__ float W2s[64][65];
    __shared__ float gi[4][64];
    __shared__ float gu[4][64];
    const int tid = threadIdx.x;
    for (int t = tid; t < 64 * 64; t += 256) W2s[t >> 6][t & 63] = W2[t];
    const int r4 = tid >> 6, d = tid & 63;
    for (int p = 0; p < 4; ++p) {
        const int row = blockIdx.x * 16 + p * 4 + r4;
        const float invr = rsqrtf(rs[row]);
        const float invc = rsqrtf(cs[row]);
        const float u_rd = user[(size_t)row * 64 + d];
        const float i_rd = item[(size_t)row * 64 + d];
        float pi_lo = 0.f, pi_hi = 0.f, pu_lo = 0.f, pu_hi = 0.f;
#pragma unroll
        for (int s = 0; s < KSPLIT; ++s) {
            const size_t off = (size_t)s * N * 128 + (size_t)row * 128;
            pi_lo += Pi[off + d];
            pi_hi += Pi[off + 64 + d];
            pu_lo += Pu[off + d];
            pu_hi += Pu[off + 64 + d];
        }
        __syncthreads();
        gi[r4][d] = u_rd * invr * pi_hi;
        gu[r4][d] = i_rd * invc * pu_hi;
        __syncthreads();
        float vi = invr * pi_lo + i_rd;
        float vu = invc * pu_lo + u_rd;
#pragma unroll
        for (int e = 0; e < 64; ++e) {
            vi += gi[r4][e] * W2s[e][d];
            vu += gu[r4][e] * W2s[e][d];
        }
        vi = vi > 0.f ? vi : LRELU_ALPHA * vi;
        vu = vu > 0.f ? vu : LRELU_ALPHA * vu;
        out[(size_t)row * 64 + d] = vu;
        out[(size_t)N * 64 + (size_t)row * 64 + d] = vi;
    }
}

extern "C" void kernel_launch(void* const* d_in, const int* in_sizes, int n_in,
                              void* d_out, int out_size, void* d_ws, size_t ws_size,
                              hipStream_t stream) {
    const float* user = (const float*)d_in[0];
    const float* item = (const float*)d_in[1];
    const float* adj  = (const float*)d_in[2];
    const float* W1   = (const float*)d_in[3];
    const float* W2   = (const float*)d_in[4];
    float* out = (float*)d_out;

    char* w = (char*)d_ws;
    float* Pi = (float*)w;  w += (size_t)KSPLIT * N * 128 * 4;   // 32 MB
    float* Pu = (float*)w;  w += (size_t)KSPLIT * N * 128 * 4;   // 32 MB
    float* rs = (float*)w;  w += (size_t)N * 4;
    float* cs = (float*)w;  w += (size_t)N * 4;
    unsigned short* Bti = (unsigned short*)w;  w += (size_t)N * 128 * 2;
    unsigned short* Btu = (unsigned short*)w;  w += (size_t)N * 128 * 2;
    unsigned short* adjbf = (unsigned short*)w;

    // only rs/cs need zero-init (P slices are fully overwritten)
    (void)hipMemsetAsync(rs, 0, (size_t)2 * N * 4, stream);

    pass1_kernel<<<dim3(N / 128, N / 128), 256, 0, stream>>>(adj, rs, cs, adjbf);
    prep_kernel<<<N / 64, 256, 0, stream>>>(user, item, W1, rs, cs, Bti, Btu);
    gemm_kernel<<<dim3(N / 128, KSPLIT, 2), 256, 0, stream>>>(adjbf, Bti, Btu, Pi, Pu);
    epilogue_kernel<<<N / 16, 256, 0, stream>>>(user, item, W2, rs, cs, Pi, Pu, out);
}

// Round 7
// 510.665 us; speedup vs baseline: 1.0155x; 1.0009x over previous
//
#include <hip/hip_runtime.h>
#include <hip/hip_bf16.h>

// NGCF fused propagation, N=8192, D=64.
//  pass1: read fp32 adj once -> rs, cs + adjbf (bf16)
//  prep : Bti[d][j] = invc[j]*[user@W1 | item][j][d] ; Btu[d][i] = invr[i]*[item@W1 | user][i][d]
//  gemm : z=0: Pi[s] = adjbf[:, ks] @ Bti[:, ks]^T   (private per-split slice, plain stores)
//         z=1: Pu[s] = adjbf[ks, :]^T @ Btu[:, ks]^T (transpose via swizzled LDS scatter)
//  epi  : sum slices; out = leaky( inv*P[:,0:64] + (tgt_elem*inv*P[:,64:128])@W2 + tgt )
// This round: epilogue vectorized (f32x4 global IO, ds_read_b128 W2, single barrier)
// -- was LDS-issue-bound (~768 scalar ds_read/thread), now at its BW floor.

#define LRELU_ALPHA 0.2f
constexpr int N = 8192;
constexpr int KSPLIT = 8;
constexpr int KC = N / KSPLIT;   // 1024 K per block, 16 BK-steps of 64

typedef __attribute__((ext_vector_type(4))) float f32x4;
typedef __attribute__((ext_vector_type(8))) __bf16 bf16x8;

__device__ __forceinline__ unsigned short f2bf(float x) {
    // plain cast: compiler emits v_cvt_pk_bf16_f32 (RNE) when paired
    return __builtin_bit_cast(unsigned short, (__bf16)x);
}
__device__ __forceinline__ f32x4 mfma16(uint4 a, uint4 b, f32x4 c) {
    return __builtin_amdgcn_mfma_f32_16x16x32_bf16(
        __builtin_bit_cast(bf16x8, a), __builtin_bit_cast(bf16x8, b), c, 0, 0, 0);
}
__device__ __forceinline__ void stage16(const void* g, void* l) {
    __builtin_amdgcn_global_load_lds(
        (const __attribute__((address_space(1))) unsigned int*)g,
        (__attribute__((address_space(3))) unsigned int*)l, 16, 0, 0);
}

// ---------------- pass1: sums + bf16 copy (VALU-lean) ----------------
__global__ __launch_bounds__(256) void pass1_kernel(
    const float* __restrict__ adj,
    float* __restrict__ rs, float* __restrict__ cs,
    unsigned short* __restrict__ adjbf) {
    __shared__ float rowpart[128][33];     // [row][lane-group partial], +1 pad: 2-way banks
    __shared__ float4 colpart4[8][32];
    const int tid = threadIdx.x;
    const int g32 = tid >> 5, l32 = tid & 31;
    const int r0 = blockIdx.y * 128, c0 = blockIdx.x * 128;

    float4 colacc = make_float4(0.f, 0.f, 0.f, 0.f);
#pragma unroll 4
    for (int s = 0; s < 16; ++s) {
        const int i = s * 8 + g32;
        float4 v = *reinterpret_cast<const float4*>(adj + (size_t)(r0 + i) * N + c0 + l32 * 4);
        colacc.x += v.x; colacc.y += v.y; colacc.z += v.z; colacc.w += v.w;
        ushort4 b;
        b.x = f2bf(v.x); b.y = f2bf(v.y); b.z = f2bf(v.z); b.w = f2bf(v.w);
        *reinterpret_cast<ushort4*>(adjbf + (size_t)(r0 + i) * N + c0 + l32 * 4) = b;
        rowpart[i][l32] = (v.x + v.y) + (v.z + v.w);   // 1 ds_write replaces 5x shfl+add
    }
    colpart4[g32][l32] = colacc;
    __syncthreads();

    if (tid < 128) {
        float rsum = 0.f;
#pragma unroll
        for (int w = 0; w < 32; ++w) rsum += rowpart[tid][w];
        atomicAdd(rs + r0 + tid, rsum);
        const float* cp = (const float*)colpart4;
        float s = 0.f;
#pragma unroll
        for (int w = 0; w < 8; ++w) s += cp[w * 128 + tid];
        atomicAdd(cs + c0 + tid, s);
    }
}

// ---------------- build the two RHS matrices (transposed, bf16) ----------------
__global__ __launch_bounds__(256) void prep_kernel(
    const float* __restrict__ user, const float* __restrict__ item,
    const float* __restrict__ W1, const float* __restrict__ rs, const float* __restrict__ cs,
    unsigned short* __restrict__ Bti, unsigned short* __restrict__ Btu) {
    __shared__ float W1s[64][65];
    __shared__ float ru[64][65];
    __shared__ float ri[64][65];
    __shared__ unsigned short tile[128][66];
    const int tid = threadIdx.x;
    const int j0 = blockIdx.x * 64;
    for (int t = tid; t < 64 * 64; t += 256) {
        W1s[t >> 6][t & 63] = W1[t];
        ru[t >> 6][t & 63] = user[(size_t)j0 * 64 + t];
        ri[t >> 6][t & 63] = item[(size_t)j0 * 64 + t];
    }
    __syncthreads();
    for (int pass = 0; pass < 2; ++pass) {
        for (int it = 0; it < 32; ++it) {
            int idx = tid + 256 * it;
            int d = idx & 127, jl = idx >> 7;
            float scale = (pass == 0) ? rsqrtf(cs[j0 + jl]) : rsqrtf(rs[j0 + jl]);
            float v;
            if (d < 64) {
                const float(*src)[65] = (pass == 0) ? ru : ri;
                float acc = 0.f;
#pragma unroll
                for (int k = 0; k < 64; ++k) acc += src[jl][k] * W1s[k][d];
                v = acc;
            } else {
                const float(*src)[65] = (pass == 0) ? ri : ru;
                v = src[jl][d - 64];
            }
            tile[d][jl] = f2bf(v * scale);
        }
        __syncthreads();
        unsigned short* Bt = (pass == 0) ? Bti : Btu;
        for (int t = tid; t < 128 * 64; t += 256) {
            int d = t >> 6, jl = t & 63;
            Bt[(size_t)d * N + j0 + jl] = tile[d][jl];
        }
        __syncthreads();
    }
}

// ---------------- merged gemm: z=0 N-path (Pi), z=1 T-path (Pu) ----------------
// Block: 128 out-rows x 128 cols x KC. 4 waves 2x2; each wave 64x64 (4x4 MFMA tiles).
// LDS XOR-swizzled; stores go to private per-(blockIdx.y) slices (no atomics).
__global__ __launch_bounds__(256, 3) void gemm_kernel(
    const unsigned short* __restrict__ A,
    const unsigned short* __restrict__ Bti, const unsigned short* __restrict__ Btu,
    float* __restrict__ Pi, float* __restrict__ Pu) {
    __shared__ unsigned short Xs[128 * 64];   // As (N-path) or Ts (T-path)
    __shared__ unsigned short Bs[128 * 64];

    const bool isT = blockIdx.z != 0;
    const unsigned short* __restrict__ Bt = isT ? Btu : Bti;
    float* __restrict__ Pw = (isT ? Pu : Pi) + (size_t)blockIdx.y * ((size_t)N * 128);

    const int lane = threadIdx.x & 63, wave = threadIdx.x >> 6;
    const int q = lane >> 4, lm = lane & 15;
    const int wr = wave >> 1, wc = wave & 1;
    const int x0 = blockIdx.x * 128;           // m0 (N-path) or j0 (T-path)
    const int kbase = blockIdx.y * KC;

    const int sr = wave * 32 + (lane >> 3);
    const int sc = lane & 7;

    f32x4 acc[4][4];
#pragma unroll
    for (int mt = 0; mt < 4; ++mt)
#pragma unroll
        for (int nt = 0; nt < 4; ++nt) acc[mt][nt] = (f32x4){0.f, 0.f, 0.f, 0.f};

    if (!isT) {
        // ---- N-path: Pi[m, :] = sum_k A[m, k] * Bt[:, k] ----
        for (int step = 0; step < KC / 64; ++step) {
            const int k0 = kbase + step * 64;
#pragma unroll
            for (int t = 0; t < 4; ++t) {
                const int r = sr + t * 8;
                const int koff = (sc ^ (r & 7)) * 8;
                stage16(A + (size_t)(x0 + r) * N + k0 + koff, &Xs[(wave * 32 + t * 8) * 64]);
                stage16(Bt + (size_t)r * N + k0 + koff, &Bs[(wave * 32 + t * 8) * 64]);
            }
            __syncthreads();
#pragma unroll
            for (int kk = 0; kk < 2; ++kk) {
                uint4 af[4], bf[4];
#pragma unroll
                for (int mt = 0; mt < 4; ++mt) {
                    const int ml = wr * 64 + mt * 16 + lm;
                    af[mt] = *reinterpret_cast<const uint4*>(
                        &Xs[ml * 64 + (((kk * 4 + q) ^ (ml & 7)) * 8)]);
                }
#pragma unroll
                for (int nt = 0; nt < 4; ++nt) {
                    const int nl = wc * 64 + nt * 16 + lm;
                    bf[nt] = *reinterpret_cast<const uint4*>(
                        &Bs[nl * 64 + (((kk * 4 + q) ^ (nl & 7)) * 8)]);
                }
#pragma unroll
                for (int mt = 0; mt < 4; ++mt)
#pragma unroll
                    for (int nt = 0; nt < 4; ++nt)
                        acc[mt][nt] = mfma16(af[mt], bf[nt], acc[mt][nt]);
            }
            __syncthreads();
        }
    } else {
        // ---- T-path: Pu[j, :] = sum_i A[i, j] * Bt[:, i]; transpose via LDS scatter ----
        for (int step = 0; step < KC / 64; ++step) {
            const int ibase = kbase + step * 64;
            uint4 g[4];
#pragma unroll
            for (int p = 0; p < 4; ++p) {
                const int jc = wave + p * 4;
                g[p] = *reinterpret_cast<const uint4*>(
                    A + (size_t)(ibase + lane) * N + x0 + jc * 8);
            }
            __syncthreads();   // prior step's MFMA reads done before LDS overwrite
#pragma unroll
            for (int t = 0; t < 4; ++t) {
                const int r = sr + t * 8;
                const int koff = (sc ^ (r & 7)) * 8;
                stage16(Bt + (size_t)r * N + ibase + koff, &Bs[(wave * 32 + t * 8) * 64]);
            }
            // transposed scatter: per instr j wave-uniform, lanes span i=0..63 contiguous
#pragma unroll
            for (int p = 0; p < 4; ++p) {
                const int jl = (wave + p * 4) * 8;
                const unsigned short* e = reinterpret_cast<const unsigned short*>(&g[p]);
#pragma unroll
                for (int k = 0; k < 8; ++k) {
                    Xs[(jl + k) * 64 + (lane ^ (k * 8))] = e[k];
                }
            }
            __syncthreads();
#pragma unroll
            for (int kk = 0; kk < 2; ++kk) {
                uint4 af[4], bf[4];
#pragma unroll
                for (int mt = 0; mt < 4; ++mt) {
                    const int ml = wr * 64 + mt * 16 + lm;
                    af[mt] = *reinterpret_cast<const uint4*>(
                        &Xs[ml * 64 + ((kk * 32 + q * 8) ^ ((ml & 7) * 8))]);
                }
#pragma unroll
                for (int nt = 0; nt < 4; ++nt) {
                    const int nl = wc * 64 + nt * 16 + lm;
                    bf[nt] = *reinterpret_cast<const uint4*>(
                        &Bs[nl * 64 + (((kk * 4 + q) ^ (nl & 7)) * 8)]);
                }
#pragma unroll
                for (int mt = 0; mt < 4; ++mt)
#pragma unroll
                    for (int nt = 0; nt < 4; ++nt)
                        acc[mt][nt] = mfma16(af[mt], bf[nt], acc[mt][nt]);
            }
        }
    }

#pragma unroll
    for (int mt = 0; mt < 4; ++mt)
#pragma unroll
        for (int nt = 0; nt < 4; ++nt)
#pragma unroll
            for (int r = 0; r < 4; ++r) {
                const int row = x0 + wr * 64 + mt * 16 + q * 4 + r;
                const int col = wc * 64 + nt * 16 + lm;
                Pw[(size_t)row * 128 + col] = acc[mt][nt][r];
            }
}

// ---------------- epilogue: slice-sum, scale, (g)@W2, +tgt, leaky, write ----------------
// Vectorized: thread owns (row rl = tid>>4, d4 = (tid&15)*4). f32x4 global IO,
// ds_read_b128 on W2s (padded [64][68]: 16B-aligned, 2-way banks = free), 1 barrier.
__global__ __launch_bounds__(256) void epilogue_kernel(
    const float* __restrict__ user, const float* __restrict__ item,
    const float* __restrict__ W2, const float* __restrict__ rs, const float* __restrict__ cs,
    const float* __restrict__ Pi, const float* __restrict__ Pu,
    float* __restrict__ out) {
    __shared__ float W2s[64][68];
    __shared__ float gi[16][68];
    __shared__ float gu[16][68];
    const int tid = threadIdx.x;
    const int rl = tid >> 4;          // local row 0..15
    const int t16 = tid & 15;
    const int d4 = t16 * 4;           // column group
    const int row = blockIdx.x * 16 + rl;

    // stage W2 (1 KiB/wave-instr coalesced)
    for (int t = tid; t < 64 * 16; t += 256) {
        const int e = t >> 4, c = (t & 15) * 4;
        const f32x4 w = *reinterpret_cast<const f32x4*>(W2 + e * 64 + c);
        *reinterpret_cast<f32x4*>(&W2s[e][c]) = w;
    }

    const float invr = rsqrtf(rs[row]);
    const float invc = rsqrtf(cs[row]);
    const f32x4 u4 = *reinterpret_cast<const f32x4*>(user + (size_t)row * 64 + d4);
    const f32x4 i4 = *reinterpret_cast<const f32x4*>(item + (size_t)row * 64 + d4);

    // slice-sum (s ascending: same order as before -> identical numerics)
    f32x4 pi_lo = (f32x4){0.f, 0.f, 0.f, 0.f}, pi_hi = pi_lo;
    f32x4 pu_lo = pi_lo, pu_hi = pi_lo;
#pragma unroll
    for (int s = 0; s < KSPLIT; ++s) {
        const size_t off = (size_t)s * N * 128 + (size_t)row * 128 + d4;
        pi_lo += *reinterpret_cast<const f32x4*>(Pi + off);
        pi_hi += *reinterpret_cast<const f32x4*>(Pi + off + 64);
        pu_lo += *reinterpret_cast<const f32x4*>(Pu + off);
        pu_hi += *reinterpret_cast<const f32x4*>(Pu + off + 64);
    }

    *reinterpret_cast<f32x4*>(&gi[rl][d4]) = u4 * invr * pi_hi;
    *reinterpret_cast<f32x4*>(&gu[rl][d4]) = i4 * invc * pu_hi;
    __syncthreads();

    f32x4 vi = invr * pi_lo + i4;
    f32x4 vu = invc * pu_lo + u4;
#pragma unroll 8
    for (int e = 0; e < 64; ++e) {
        const f32x4 w = *reinterpret_cast<const f32x4*>(&W2s[e][d4]);  // b128, 2-way banks
        const float gie = gi[rl][e];   // broadcast
        const float gue = gu[rl][e];   // broadcast
        vi += gie * w;
        vu += gue * w;
    }
#pragma unroll
    for (int c = 0; c < 4; ++c) {
        vi[c] = vi[c] > 0.f ? vi[c] : LRELU_ALPHA * vi[c];
        vu[c] = vu[c] > 0.f ? vu[c] : LRELU_ALPHA * vu[c];
    }
    *reinterpret_cast<f32x4*>(out + (size_t)row * 64 + d4) = vu;
    *reinterpret_cast<f32x4*>(out + (size_t)N * 64 + (size_t)row * 64 + d4) = vi;
}

extern "C" void kernel_launch(void* const* d_in, const int* in_sizes, int n_in,
                              void* d_out, int out_size, void* d_ws, size_t ws_size,
                              hipStream_t stream) {
    const float* user = (const float*)d_in[0];
    const float* item = (const float*)d_in[1];
    const float* adj  = (const float*)d_in[2];
    const float* W1   = (const float*)d_in[3];
    const float* W2   = (const float*)d_in[4];
    float* out = (float*)d_out;

    char* w = (char*)d_ws;
    float* Pi = (float*)w;  w += (size_t)KSPLIT * N * 128 * 4;   // 32 MB
    float* Pu = (float*)w;  w += (size_t)KSPLIT * N * 128 * 4;   // 32 MB
    float* rs = (float*)w;  w += (size_t)N * 4;
    float* cs = (float*)w;  w += (size_t)N * 4;
    unsigned short* Bti = (unsigned short*)w;  w += (size_t)N * 128 * 2;
    unsigned short* Btu = (unsigned short*)w;  w += (size_t)N * 128 * 2;
    unsigned short* adjbf = (unsigned short*)w;

    // only rs/cs need zero-init (P slices are fully overwritten)
    (void)hipMemsetAsync(rs, 0, (size_t)2 * N * 4, stream);

    pass1_kernel<<<dim3(N / 128, N / 128), 256, 0, stream>>>(adj, rs, cs, adjbf);
    prep_kernel<<<N / 64, 256, 0, stream>>>(user, item, W1, rs, cs, Bti, Btu);
    gemm_kernel<<<dim3(N / 128, KSPLIT, 2), 256, 0, stream>>>(adjbf, Bti, Btu, Pi, Pu);
    epilogue_kernel<<<N / 16, 256, 0, stream>>>(user, item, W2, rs, cs, Pi, Pu, out);
}